// Round 16
// baseline (283.600 us; speedup 1.0000x reference)
//
#include <hip/hip_runtime.h>
#include <math.h>

#define NN 50000      // nodes (both src and dst)
#define DIN 128
#define FDIM 256      // H*C
#define EE 200000
#define TT 6
#define DE 8
#define KC 48         // clusters
#define NB ((NN + 255)/256)   // 196 scan blocks
#define CDB ((EE + 255)/256)  // 782 count blocks

typedef __attribute__((ext_vector_type(8))) short bf16x8;
typedef __attribute__((ext_vector_type(8))) unsigned short u16x8;
typedef __attribute__((ext_vector_type(4))) float f32x4;

// f32 -> bf16 round-to-nearest-even
__device__ inline unsigned short f2b(float f){
  unsigned u = __float_as_uint(f);
  unsigned r = u + 0x7FFFu + ((u >> 16) & 1u);
  return (unsigned short)(r >> 16);
}
// bf16 -> f32
__device__ inline float b2f(unsigned short u){ return __uint_as_float(((unsigned)u) << 16); }

// ---------------- init: weight transposes (y=0..3) + deg/aggE zero (y=4) ----------------
__global__ void init_misc(const float* __restrict__ W1s, const float* __restrict__ W2s,
                          const float* __restrict__ W1d, const float* __restrict__ W2d,
                          unsigned short* __restrict__ Wtall, unsigned short* __restrict__ Wt2d,
                          int* __restrict__ deg, int* __restrict__ aggE){
  int n = blockIdx.x;
  int which = blockIdx.y;
  if (which == 4){
    int i = n*256 + threadIdx.x;
    if (i < NN) deg[i] = 0;
    if (i < 64) aggE[i] = 0;
  } else if (which == 3){
    for (int k = threadIdx.x; k < FDIM; k += 256)
      Wt2d[(size_t)n*FDIM + k] = f2b(W2d[(size_t)k*256 + n]);
  } else {
    const float* W = (which == 0) ? W1s : (which == 1) ? W2s : W1d;
    unsigned short* o = Wtall + (size_t)which*256*DIN + (size_t)n*DIN;
    for (int k = threadIdx.x; k < DIN; k += 256)
      o[k] = f2b(W[(size_t)k*256 + n]);
  }
}

// ---------------- count_deg (blocks 0..CDB-1) + edge_attr_mean (blocks CDB..) ----------------
#define BPT 128
__global__ __launch_bounds__(256) void count_and_mean(const int* __restrict__ dst, int* __restrict__ deg,
                                                      const float* __restrict__ ea, float* __restrict__ aggE){
  int b = blockIdx.x;
  if (b < CDB){
    int i = b*256 + threadIdx.x;
    if (i < EE) atomicAdd(&deg[dst[i]], 1);
    return;
  }
  int bb = b - CDB;                 // 0..TT*BPT-1
  int t   = bb / BPT;
  int blk = bb % BPT;
  const int NF4 = EE * 2;
  const int per_blk = (NF4 + BPT - 1) / BPT;
  int i0 = blk * per_blk;
  int i1 = min(i0 + per_blk, NF4);
  const float4* base = (const float4*)(ea + (size_t)t*EE*DE);
  float s[8] = {0,0,0,0,0,0,0,0};
  for (int i = i0 + (int)threadIdx.x; i < i1; i += 256){
    float4 v = base[i];
    int db = (i & 1) * 4;
    s[db+0] += v.x; s[db+1] += v.y; s[db+2] += v.z; s[db+3] += v.w;
  }
  __shared__ float red[256];
  for (int d = 0; d < 8; d++){
    red[threadIdx.x] = s[d];
    __syncthreads();
    for (int off = 128; off > 0; off >>= 1){
      if (threadIdx.x < (unsigned)off) red[threadIdx.x] += red[threadIdx.x + off];
      __syncthreads();
    }
    if (threadIdx.x == 0) atomicAdd(&aggE[t*DE + d], red[0] / (float)EE);
    __syncthreads();
  }
}

// ---------------- hierarchical exclusive scan (2 kernels) ----------------
__global__ __launch_bounds__(256) void scan_blk(const int* __restrict__ deg, int* __restrict__ rp,
                                                int* __restrict__ bsum){
  __shared__ int sm[256];
  int i = blockIdx.x*256 + threadIdx.x;
  int v = (i < NN) ? deg[i] : 0;
  sm[threadIdx.x] = v;
  __syncthreads();
  #pragma unroll
  for (int off = 1; off < 256; off <<= 1){
    int t = (threadIdx.x >= (unsigned)off) ? sm[threadIdx.x - off] : 0;
    __syncthreads();
    sm[threadIdx.x] += t;
    __syncthreads();
  }
  if (i < NN) rp[i] = sm[threadIdx.x] - v;   // block-local exclusive
  if (threadIdx.x == 255) bsum[blockIdx.x] = sm[255];
}

// each block computes its own prefix of bsum (NB=196 <= 256: one LDS reduce pass)
__global__ __launch_bounds__(256) void scan_add(int* __restrict__ rp, const int* __restrict__ bsum,
                                                int* __restrict__ cursor){
  __shared__ int red[256];
  int t = threadIdx.x;
  red[t] = (t < (int)blockIdx.x) ? bsum[t] : 0;
  __syncthreads();
  #pragma unroll
  for (int off = 128; off > 0; off >>= 1){
    if (t < off) red[t] += red[t + off];
    __syncthreads();
  }
  int boffs = red[0];
  int i = blockIdx.x*256 + t;
  if (i < NN){
    int r = rp[i] + boffs;
    rp[i] = r;
    cursor[i] = r;
  }
  if (i == 0) rp[NN] = EE;
}

// scatter SRC VALUES (not edge ids): removes one indirection in the fused edge loop
__global__ void scatter_edges(const int* __restrict__ src, const int* __restrict__ dst,
                              int* __restrict__ cursor, int* __restrict__ srt){
  int i = blockIdx.x*256 + threadIdx.x;
  if (i < EE){ int pos = atomicAdd(&cursor[dst[i]], 1); srt[pos] = src[i]; }
}

// ---------------- layer-1 GEMMs with shared A strip in LDS ----------------
// grid (392, 2). y=0: A=x_pkg, 4 tiles (hs1 c0/c1, hs2 c0/c1). y=1: A=xd5, 2 tiles (hd1).
__global__ __launch_bounds__(256) void gemm_l1(const float* __restrict__ Apkg, const float* __restrict__ Adst,
                                               const unsigned short* __restrict__ Wtall,
                                               const float* __restrict__ mask,
                                               unsigned short* __restrict__ Chs1,
                                               unsigned short* __restrict__ Chs2,
                                               unsigned short* __restrict__ Chd1){
  __shared__ short Afull[128][136];
  __shared__ short Bl[128][56];
  int tid = threadIdx.x;
  int lane = tid & 63;
  int w = tid >> 6;
  int wm = w >> 1, wn = w & 1;
  int row0 = blockIdx.x * 128;
  int fr = lane & 15;
  int kb = lane >> 4;
  const float* A = blockIdx.y ? Adst : Apkg;
  #pragma unroll
  for (int p = 0; p < 8; p++){
    int idx = tid + p*256;
    int r = idx >> 4, ch = idx & 15;
    int gr = row0 + r;
    u16x8 o = (u16x8){0,0,0,0,0,0,0,0};
    if (gr < NN){
      float mv = mask[gr];
      const float* ap = A + (size_t)gr*DIN + ch*8;
      float4 a0 = *(const float4*)(ap);
      float4 a1 = *(const float4*)(ap + 4);
      o[0]=f2b(a0.x*mv); o[1]=f2b(a0.y*mv); o[2]=f2b(a0.z*mv); o[3]=f2b(a0.w*mv);
      o[4]=f2b(a1.x*mv); o[5]=f2b(a1.y*mv); o[6]=f2b(a1.z*mv); o[7]=f2b(a1.w*mv);
    }
    *(u16x8*)(&Afull[r][ch*8]) = o;
  }
  int ntile = blockIdx.y ? 2 : 4;
  #pragma unroll 1
  for (int t = 0; t < ntile; t++){
    int wsel = blockIdx.y ? 2 : (t >> 1);
    const unsigned short* Wt = Wtall + (size_t)wsel*256*DIN;
    unsigned short* Co = blockIdx.y ? Chd1 : ((t >> 1) ? Chs2 : Chs1);
    int col0 = (t & 1) * 128;
    f32x4 acc[4][4];
    #pragma unroll
    for (int i = 0; i < 4; i++)
      #pragma unroll
      for (int j = 0; j < 4; j++)
        acc[i][j] = (f32x4){0.f, 0.f, 0.f, 0.f};
    for (int k0 = 0; k0 < DIN; k0 += 32){
      bf16x8 rb[2];
      #pragma unroll
      for (int p = 0; p < 2; p++){
        int idx = tid + p*256;
        int r = idx >> 2, ch = idx & 3;
        rb[p] = *(const bf16x8*)(Wt + (size_t)(col0 + r)*DIN + k0 + ch*8);
      }
      __syncthreads();
      #pragma unroll
      for (int p = 0; p < 2; p++){
        int idx = tid + p*256;
        int r = idx >> 2, ch = idx & 3;
        *(bf16x8*)(&Bl[r][ch*8]) = rb[p];
      }
      __syncthreads();
      bf16x8 af[4], bfr[4];
      #pragma unroll
      for (int i = 0; i < 4; i++) af[i]  = *(const bf16x8*)(&Afull[wm*64 + i*16 + fr][k0 + kb*8]);
      #pragma unroll
      for (int j = 0; j < 4; j++) bfr[j] = *(const bf16x8*)(&Bl[wn*64 + j*16 + fr][kb*8]);
      #pragma unroll
      for (int i = 0; i < 4; i++)
        #pragma unroll
        for (int j = 0; j < 4; j++)
          acc[i][j] = __builtin_amdgcn_mfma_f32_16x16x32_bf16(af[i], bfr[j], acc[i][j], 0, 0, 0);
    }
    // C/D layout: col = lane&15, row = (lane>>4)*4 + q  (m89-verified)
    #pragma unroll
    for (int i = 0; i < 4; i++){
      #pragma unroll
      for (int q = 0; q < 4; q++){
        int grow = row0 + wm*64 + i*16 + kb*4 + q;
        if (grow < NN){
          #pragma unroll
          for (int j = 0; j < 4; j++)
            Co[(size_t)grow*256 + col0 + wn*64 + j*16 + fr] = f2b(acc[i][j][q]);
        }
      }
    }
  }
}

// ---------------- MFMA GEMM, bf16 A (h1 @ W2_dst), K=256 ----------------
__global__ __launch_bounds__(256) void gemm_bf16(const short* __restrict__ A, const short* __restrict__ Wt,
                                                 unsigned short* __restrict__ Cb, int M, int K){
  __shared__ short Al[128][56];
  __shared__ short Bl[128][56];
  int tid = threadIdx.x;
  int lane = tid & 63;
  int w = tid >> 6;
  int wm = w >> 1, wn = w & 1;
  int row0 = blockIdx.x * 128, col0 = blockIdx.y * 128;
  int fr = lane & 15;
  int kb = lane >> 4;
  f32x4 acc[4][4];
  #pragma unroll
  for (int i = 0; i < 4; i++)
    #pragma unroll
    for (int j = 0; j < 4; j++)
      acc[i][j] = (f32x4){0.f, 0.f, 0.f, 0.f};

  for (int k0 = 0; k0 < K; k0 += 32){
    bf16x8 ra[2], rb[2];
    #pragma unroll
    for (int p = 0; p < 2; p++){
      int idx = tid + p*256;
      int r = idx >> 2, ch = idx & 3;
      int gr = row0 + r;
      if (gr < M) ra[p] = *(const bf16x8*)(A + (size_t)gr*K + k0 + ch*8);
      else        ra[p] = (bf16x8){0,0,0,0,0,0,0,0};
      rb[p] = *(const bf16x8*)(Wt + (size_t)(col0 + r)*K + k0 + ch*8);
    }
    __syncthreads();
    #pragma unroll
    for (int p = 0; p < 2; p++){
      int idx = tid + p*256;
      int r = idx >> 2, ch = idx & 3;
      *(bf16x8*)(&Al[r][ch*8]) = ra[p];
      *(bf16x8*)(&Bl[r][ch*8]) = rb[p];
    }
    __syncthreads();
    bf16x8 af[4], bfr[4];
    #pragma unroll
    for (int i = 0; i < 4; i++) af[i]  = *(const bf16x8*)(&Al[wm*64 + i*16 + fr][kb*8]);
    #pragma unroll
    for (int j = 0; j < 4; j++) bfr[j] = *(const bf16x8*)(&Bl[wn*64 + j*16 + fr][kb*8]);
    #pragma unroll
    for (int i = 0; i < 4; i++)
      #pragma unroll
      for (int j = 0; j < 4; j++)
        acc[i][j] = __builtin_amdgcn_mfma_f32_16x16x32_bf16(af[i], bfr[j], acc[i][j], 0, 0, 0);
  }
  #pragma unroll
  for (int i = 0; i < 4; i++){
    #pragma unroll
    for (int q = 0; q < 4; q++){
      int grow = row0 + wm*64 + i*16 + kb*4 + q;
      if (grow < M){
        #pragma unroll
        for (int j = 0; j < 4; j++)
          Cb[(size_t)grow*256 + col0 + wn*64 + j*16 + fr] = f2b(acc[i][j][q]);
      }
    }
  }
}

// ---------------- FUSED GAT edge phase: logits + exp + weighted aggregation ----------------
// Wave per dst node; srt[] = pre-gathered src ids. Unrolled x4 (mean degree = 4).
__global__ __launch_bounds__(256) void gat_fused(const int* __restrict__ rp, const int* __restrict__ srt,
                                                 const unsigned short* __restrict__ hs,
                                                 const unsigned short* __restrict__ hd,
                                                 const float* __restrict__ att, const float* __restrict__ bias,
                                                 unsigned short* __restrict__ outb, int do_relu){
  int n = blockIdx.x*4 + (threadIdx.x >> 6);
  int lane = threadIdx.x & 63;
  if (n >= NN) return;
  const float4 av = *(const float4*)(att + lane*4);
  ushort4 ud = *(const ushort4*)(hd + (size_t)n*256 + lane*4);
  float d0 = b2f(ud.x), d1 = b2f(ud.y), d2 = b2f(ud.z), d3 = b2f(ud.w);
  int beg = rp[n], end = rp[n+1];
  float4 acc = {0.f,0.f,0.f,0.f};
  float sw = 0.f;
  int i = beg;
  for (; i + 3 < end; i += 4){
    int sA = srt[i], sB = srt[i+1], sC = srt[i+2], sD = srt[i+3];
    ushort4 uA = *(const ushort4*)(hs + (size_t)sA*256 + lane*4);
    ushort4 uB = *(const ushort4*)(hs + (size_t)sB*256 + lane*4);
    ushort4 uC = *(const ushort4*)(hs + (size_t)sC*256 + lane*4);
    ushort4 uD = *(const ushort4*)(hs + (size_t)sD*256 + lane*4);
    float hA0=b2f(uA.x), hA1=b2f(uA.y), hA2=b2f(uA.z), hA3=b2f(uA.w);
    float hB0=b2f(uB.x), hB1=b2f(uB.y), hB2=b2f(uB.z), hB3=b2f(uB.w);
    float hC0=b2f(uC.x), hC1=b2f(uC.y), hC2=b2f(uC.z), hC3=b2f(uC.w);
    float hD0=b2f(uD.x), hD1=b2f(uD.y), hD2=b2f(uD.z), hD3=b2f(uD.w);
    float mA0=hA0+d0, mA1=hA1+d1, mA2=hA2+d2, mA3=hA3+d3;
    float mB0=hB0+d0, mB1=hB1+d1, mB2=hB2+d2, mB3=hB3+d3;
    float mC0=hC0+d0, mC1=hC1+d1, mC2=hC2+d2, mC3=hC3+d3;
    float mD0=hD0+d0, mD1=hD1+d1, mD2=hD2+d2, mD3=hD3+d3;
    mA0=(mA0>0.f)?mA0:0.2f*mA0; mB0=(mB0>0.f)?mB0:0.2f*mB0; mC0=(mC0>0.f)?mC0:0.2f*mC0; mD0=(mD0>0.f)?mD0:0.2f*mD0;
    mA1=(mA1>0.f)?mA1:0.2f*mA1; mB1=(mB1>0.f)?mB1:0.2f*mB1; mC1=(mC1>0.f)?mC1:0.2f*mC1; mD1=(mD1>0.f)?mD1:0.2f*mD1;
    mA2=(mA2>0.f)?mA2:0.2f*mA2; mB2=(mB2>0.f)?mB2:0.2f*mB2; mC2=(mC2>0.f)?mC2:0.2f*mC2; mD2=(mD2>0.f)?mD2:0.2f*mD2;
    mA3=(mA3>0.f)?mA3:0.2f*mA3; mB3=(mB3>0.f)?mB3:0.2f*mB3; mC3=(mC3>0.f)?mC3:0.2f*mC3; mD3=(mD3>0.f)?mD3:0.2f*mD3;
    float pA = mA0*av.x + mA1*av.y + mA2*av.z + mA3*av.w;
    float pB = mB0*av.x + mB1*av.y + mB2*av.z + mB3*av.w;
    float pC = mC0*av.x + mC1*av.y + mC2*av.z + mC3*av.w;
    float pD = mD0*av.x + mD1*av.y + mD2*av.z + mD3*av.w;
    #pragma unroll
    for (int msk = 8; msk > 0; msk >>= 1){
      pA += __shfl_xor(pA, msk); pB += __shfl_xor(pB, msk);
      pC += __shfl_xor(pC, msk); pD += __shfl_xor(pD, msk);
    }
    float wA = expf(fminf(pA, 80.f));
    float wB = expf(fminf(pB, 80.f));
    float wC = expf(fminf(pC, 80.f));
    float wD = expf(fminf(pD, 80.f));
    acc.x = fmaf(wA, hA0, fmaf(wB, hB0, fmaf(wC, hC0, fmaf(wD, hD0, acc.x))));
    acc.y = fmaf(wA, hA1, fmaf(wB, hB1, fmaf(wC, hC1, fmaf(wD, hD1, acc.y))));
    acc.z = fmaf(wA, hA2, fmaf(wB, hB2, fmaf(wC, hC2, fmaf(wD, hD2, acc.z))));
    acc.w = fmaf(wA, hA3, fmaf(wB, hB3, fmaf(wC, hC3, fmaf(wD, hD3, acc.w))));
    sw += (wA + wB) + (wC + wD);
  }
  for (; i < end; i++){
    int s = srt[i];
    ushort4 uh = *(const ushort4*)(hs + (size_t)s*256 + lane*4);
    float h0 = b2f(uh.x), h1 = b2f(uh.y), h2 = b2f(uh.z), h3 = b2f(uh.w);
    float m0 = h0 + d0, m1 = h1 + d1, m2 = h2 + d2, m3 = h3 + d3;
    m0 = (m0 > 0.f) ? m0 : 0.2f*m0;
    m1 = (m1 > 0.f) ? m1 : 0.2f*m1;
    m2 = (m2 > 0.f) ? m2 : 0.2f*m2;
    m3 = (m3 > 0.f) ? m3 : 0.2f*m3;
    float p = m0*av.x + m1*av.y + m2*av.z + m3*av.w;
    #pragma unroll
    for (int msk = 8; msk > 0; msk >>= 1) p += __shfl_xor(p, msk);
    float wv = expf(fminf(p, 80.f));
    acc.x = fmaf(wv, h0, acc.x);
    acc.y = fmaf(wv, h1, acc.y);
    acc.z = fmaf(wv, h2, acc.z);
    acc.w = fmaf(wv, h3, acc.w);
    sw += wv;
  }
  float inv = 1.f / (sw + 1e-16f);
  const float4 b4 = *(const float4*)(bias + lane*4);
  float4 r;
  r.x = acc.x*inv + b4.x;
  r.y = acc.y*inv + b4.y;
  r.z = acc.z*inv + b4.z;
  r.w = acc.w*inv + b4.w;
  if (do_relu){
    r.x = fmaxf(r.x, 0.f); r.y = fmaxf(r.y, 0.f);
    r.z = fmaxf(r.z, 0.f); r.w = fmaxf(r.w, 0.f);
  }
  ushort4 o;
  o.x = f2b(r.x); o.y = f2b(r.y); o.z = f2b(r.z); o.w = f2b(r.w);
  *(ushort4*)(outb + (size_t)n*256 + lane*4) = o;
}

// ---------------- pool logits via MFMA + in-register row softmax -> sass bf16 [NN][48] ----------------
__global__ __launch_bounds__(256) void pool_logits_mfma(const unsigned short* __restrict__ h2b,
                                                        const float* __restrict__ Wp,
                                                        const float* __restrict__ bp,
                                                        unsigned short* __restrict__ sass,
                                                        float* __restrict__ xp){
  __shared__ short Al[128][56];    // h2 tile, BK=32
  __shared__ short Bn[KC][264];    // Wp^T, full K=256 (pad 8)
  int tid = threadIdx.x;
  int lane = tid & 63;
  int w = tid >> 6;
  int row0 = blockIdx.x * 128;
  int fr = lane & 15;
  int kb = lane >> 4;
  if (blockIdx.x == 0){
    for (int i = tid; i < KC*FDIM; i += 256) xp[i] = 0.f;
  }
  for (int idx = tid; idx < 256*KC; idx += 256){
    int k = idx / KC, n = idx % KC;
    Bn[n][k] = f2b(Wp[idx]);
  }
  f32x4 acc[2][3];
  #pragma unroll
  for (int i = 0; i < 2; i++)
    #pragma unroll
    for (int j = 0; j < 3; j++)
      acc[i][j] = (f32x4){0.f, 0.f, 0.f, 0.f};

  for (int k0 = 0; k0 < 256; k0 += 32){
    bf16x8 ra[2];
    #pragma unroll
    for (int p = 0; p < 2; p++){
      int idx = tid + p*256;
      int r = idx >> 2, ch = idx & 3;
      int gr = row0 + r;
      if (gr < NN) ra[p] = *(const bf16x8*)((const short*)h2b + (size_t)gr*256 + k0 + ch*8);
      else         ra[p] = (bf16x8){0,0,0,0,0,0,0,0};
    }
    __syncthreads();
    #pragma unroll
    for (int p = 0; p < 2; p++){
      int idx = tid + p*256;
      int r = idx >> 2, ch = idx & 3;
      *(bf16x8*)(&Al[r][ch*8]) = ra[p];
    }
    __syncthreads();
    bf16x8 af[2], bfr[3];
    #pragma unroll
    for (int i = 0; i < 2; i++) af[i]  = *(const bf16x8*)(&Al[w*32 + i*16 + fr][kb*8]);
    #pragma unroll
    for (int j = 0; j < 3; j++) bfr[j] = *(const bf16x8*)(&Bn[j*16 + fr][k0 + kb*8]);
    #pragma unroll
    for (int i = 0; i < 2; i++)
      #pragma unroll
      for (int j = 0; j < 3; j++)
        acc[i][j] = __builtin_amdgcn_mfma_f32_16x16x32_bf16(af[i], bfr[j], acc[i][j], 0, 0, 0);
  }
  float bb[3];
  #pragma unroll
  for (int j = 0; j < 3; j++) bb[j] = bp[j*16 + fr];
  #pragma unroll
  for (int i = 0; i < 2; i++){
    #pragma unroll
    for (int q = 0; q < 4; q++){
      int grow = row0 + w*32 + i*16 + kb*4 + q;
      float v0 = acc[i][0][q] + bb[0];
      float v1 = acc[i][1][q] + bb[1];
      float v2 = acc[i][2][q] + bb[2];
      float m = fmaxf(v0, fmaxf(v1, v2));
      #pragma unroll
      for (int msk = 8; msk > 0; msk >>= 1) m = fmaxf(m, __shfl_xor(m, msk));
      float e0 = expf(v0 - m), e1 = expf(v1 - m), e2 = expf(v2 - m);
      float s = e0 + e1 + e2;
      #pragma unroll
      for (int msk = 8; msk > 0; msk >>= 1) s += __shfl_xor(s, msk);
      float inv = 1.f / s;
      if (grow < NN){
        unsigned short* so = sass + (size_t)grow*KC;
        so[fr]      = f2b(e0 * inv);
        so[16 + fr] = f2b(e1 * inv);
        so[32 + fr] = f2b(e2 * inv);
      }
    }
  }
}

// ---------------- x_pooled: s.T @ h2 over 64-node chunks, direct atomic accumulate ----------------
// xp pre-zeroed by pool_logits_mfma block 0 (prior dispatch, stream-ordered). 782 contenders
// spread over 12288 addresses - benign. Eliminates the 38.4 MB partial read-back + one dispatch.
#define PCH 64
#define NPART ((NN + PCH - 1)/PCH)   // 782
__global__ __launch_bounds__(256) void pooled_partial(const unsigned short* __restrict__ sass,
                                                      const unsigned short* __restrict__ h2b,
                                                      float* __restrict__ xp){
  __shared__ float sld[PCH][KC];
  int t = threadIdx.x;
  int base = blockIdx.x * PCH;
  int cnt = min(PCH, NN - base);
  for (int idx = t; idx < cnt*KC; idx += 256)
    sld[idx/KC][idx%KC] = b2f(sass[(size_t)(base + idx/KC)*KC + idx%KC]);
  __syncthreads();
  float acc[KC];
  #pragma unroll
  for (int k = 0; k < KC; k++) acc[k] = 0.f;
  for (int n = 0; n < cnt; n++){
    float v = b2f(h2b[(size_t)(base + n)*256 + t]);
    #pragma unroll
    for (int k = 0; k < KC; k++) acc[k] = fmaf(sld[n][k], v, acc[k]);
  }
  #pragma unroll
  for (int k = 0; k < KC; k++) atomicAdd(&xp[k*256 + t], acc[k]);
}

// ---------------- final classifier ----------------
__global__ void final_cls(const float* __restrict__ xp, const float* __restrict__ agg,
                          const float* __restrict__ Wc, const float* __restrict__ bc,
                          float* __restrict__ out){
  int k = threadIdx.x;
  if (k < KC){
    float s = bc[0];
    for (int f = 0; f < 256; f++) s = fmaf(xp[k*256 + f], Wc[f], s);
    s = fmaf(agg[k], Wc[256], s);
    out[k] = 1.f/(1.f + expf(-s));
  }
}

extern "C" void kernel_launch(void* const* d_in, const int* in_sizes, int n_in,
                              void* d_out, int out_size, void* d_ws, size_t ws_size,
                              hipStream_t stream) {
  const float* x_pkg     = (const float*)d_in[0];
  const float* x_dst     = (const float*)d_in[1];
  const float* edge_attr = (const float*)d_in[2];
  const float* node_mask = (const float*)d_in[3];
  const float* W1_src    = (const float*)d_in[4];
  const float* W1_dst    = (const float*)d_in[5];
  const float* att1      = (const float*)d_in[6];
  const float* b1        = (const float*)d_in[7];
  const float* W2_src    = (const float*)d_in[8];
  const float* W2_dst    = (const float*)d_in[9];
  const float* att2      = (const float*)d_in[10];
  const float* b2        = (const float*)d_in[11];
  const float* W_pool    = (const float*)d_in[12];
  const float* b_pool    = (const float*)d_in[13];
  const float* W_cls     = (const float*)d_in[14];
  const float* b_cls     = (const float*)d_in[15];
  const int*   edge_index= (const int*)d_in[16];
  float* out = (float*)d_out;

  const int T5 = TT - 1;
  const float* W1s5 = W1_src + (size_t)T5*DIN*FDIM;
  const float* W1d5 = W1_dst + (size_t)T5*DIN*FDIM;
  const float* a1_5 = att1   + (size_t)T5*FDIM;
  const float* b1_5 = b1     + (size_t)T5*FDIM;
  const float* W2s5 = W2_src + (size_t)T5*DIN*FDIM;
  const float* W2d5 = W2_dst + (size_t)T5*FDIM*FDIM;
  const float* a2_5 = att2   + (size_t)T5*FDIM;
  const float* b2_5 = b2     + (size_t)T5*FDIM;
  const float* xd5  = x_dst  + (size_t)T5*NN*DIN;
  const int* src5   = edge_index + (size_t)T5*2*EE;
  const int* dst5   = src5 + EE;

  // ---- workspace layout (bf16 overlays inside three f32-sized slots) ----
  float* buf0 = (float*)d_ws;            // hs1b|hs2b (bf16)
  float* buf1 = buf0 + (size_t)NN*FDIM;  // hd1b|h1b (bf16)  -> h2b (bf16)
  float* buf2 = buf1 + (size_t)NN*FDIM;  // hd2b (bf16) -> sass (bf16 [NN][48])
  float* xpool= buf2 + (size_t)NN*FDIM;  // [KC*256]
  float* aggE = xpool + KC*FDIM;         // [64]
  int* deg    = (int*)(aggE + 64);
  int* rp     = deg + NN;
  int* cursor = rp + NN + 1;
  int* srt    = cursor + NN;             // [EE] pre-gathered src ids
  unsigned short* Wtall = (unsigned short*)(srt + EE);   // stacked [768][128]: W1s,W2s,W1d
  unsigned short* Wt2d  = Wtall + (size_t)3*256*DIN;     // [256][256]
  int* bsum = (int*)(Wt2d + (size_t)256*FDIM);   // [NB]
  // bf16 overlays:
  unsigned short* hs1b = (unsigned short*)buf0;                   // dead after L1 fused
  unsigned short* hs2b = hs1b + (size_t)NN*FDIM;                  // dead after L2 fused
  unsigned short* hd1b = (unsigned short*)buf1;                   // dead after L1 fused
  unsigned short* h1b  = hd1b + (size_t)NN*FDIM;                  // dead after hd2 gemm
  unsigned short* h2b  = (unsigned short*)buf1;                   // L2 fused output
  unsigned short* hd2b = (unsigned short*)buf2;                   // dead after L2 fused
  unsigned short* sass = (unsigned short*)buf2;                   // pool softmax out [NN][48]

  // init (weights + zeroing) and CSR build
  init_misc<<<dim3(256, 5), 256, 0, stream>>>(W1s5, W2s5, W1d5, W2d5, Wtall, Wt2d, deg, (int*)aggE);
  count_and_mean<<<CDB + TT*BPT, 256, 0, stream>>>(dst5, deg, edge_attr, aggE);
  scan_blk<<<NB, 256, 0, stream>>>(deg, rp, bsum);
  scan_add<<<NB, 256, 0, stream>>>(rp, bsum, cursor);
  scatter_edges<<<(EE+255)/256, 256, 0, stream>>>(src5, dst5, cursor, srt);

  // layer 1: hs1 | hs2 | hd1 with A strips staged once per block
  gemm_l1<<<dim3((NN + 127)/128, 2), 256, 0, stream>>>(x_pkg, xd5, Wtall, node_mask,
                                                        hs1b, hs2b, hd1b);
  gat_fused<<<NN/4, 256, 0, stream>>>(rp, srt, hs1b, hd1b, a1_5, b1_5, h1b, 1);   // h1 -> bf16

  // layer 2
  gemm_bf16<<<dim3((NN + 127)/128, 2), 256, 0, stream>>>((const short*)h1b, (const short*)Wt2d,
                                                          hd2b, NN, FDIM);          // hd2
  gat_fused<<<NN/4, 256, 0, stream>>>(rp, srt, hs2b, hd2b, a2_5, b2_5, h2b, 0);   // h2 -> bf16

  // pooling + classifier (sass overlays dead hd2b; xpool zeroed by pool_logits block 0)
  pool_logits_mfma<<<(NN + 127)/128, 256, 0, stream>>>(h2b, W_pool, b_pool, sass, xpool);
  pooled_partial<<<NPART, 256, 0, stream>>>(sass, h2b, xpool);
  final_cls<<<1, 64, 0, stream>>>(xpool, aggE, W_cls, b_cls, out);
}

// Round 17
// 269.758 us; speedup vs baseline: 1.0513x; 1.0513x over previous
//
#include <hip/hip_runtime.h>
#include <math.h>

#define NN 50000      // nodes (both src and dst)
#define DIN 128
#define FDIM 256      // H*C
#define EE 200000
#define TT 6
#define DE 8
#define KC 48         // clusters
#define NB ((NN + 255)/256)   // 196 scan blocks
#define CDB ((EE + 255)/256)  // 782 count blocks

typedef __attribute__((ext_vector_type(8))) short bf16x8;
typedef __attribute__((ext_vector_type(8))) unsigned short u16x8;
typedef __attribute__((ext_vector_type(4))) float f32x4;

// f32 -> bf16 round-to-nearest-even
__device__ inline unsigned short f2b(float f){
  unsigned u = __float_as_uint(f);
  unsigned r = u + 0x7FFFu + ((u >> 16) & 1u);
  return (unsigned short)(r >> 16);
}
// bf16 -> f32
__device__ inline float b2f(unsigned short u){ return __uint_as_float(((unsigned)u) << 16); }

// ---------------- init: weight transposes (y=0..3) + deg/aggE zero (y=4) ----------------
__global__ void init_misc(const float* __restrict__ W1s, const float* __restrict__ W2s,
                          const float* __restrict__ W1d, const float* __restrict__ W2d,
                          unsigned short* __restrict__ Wtall, unsigned short* __restrict__ Wt2d,
                          int* __restrict__ deg, int* __restrict__ aggE){
  int n = blockIdx.x;
  int which = blockIdx.y;
  if (which == 4){
    int i = n*256 + threadIdx.x;
    if (i < NN) deg[i] = 0;
    if (i < 64) aggE[i] = 0;
  } else if (which == 3){
    for (int k = threadIdx.x; k < FDIM; k += 256)
      Wt2d[(size_t)n*FDIM + k] = f2b(W2d[(size_t)k*256 + n]);
  } else {
    const float* W = (which == 0) ? W1s : (which == 1) ? W2s : W1d;
    unsigned short* o = Wtall + (size_t)which*256*DIN + (size_t)n*DIN;
    for (int k = threadIdx.x; k < DIN; k += 256)
      o[k] = f2b(W[(size_t)k*256 + n]);
  }
}

// ---------------- count_deg (blocks 0..CDB-1) + edge_attr_mean (blocks CDB..) ----------------
#define BPT 128
__global__ __launch_bounds__(256) void count_and_mean(const int* __restrict__ dst, int* __restrict__ deg,
                                                      const float* __restrict__ ea, float* __restrict__ aggE){
  int b = blockIdx.x;
  if (b < CDB){
    int i = b*256 + threadIdx.x;
    if (i < EE) atomicAdd(&deg[dst[i]], 1);
    return;
  }
  int bb = b - CDB;                 // 0..TT*BPT-1
  int t   = bb / BPT;
  int blk = bb % BPT;
  const int NF4 = EE * 2;
  const int per_blk = (NF4 + BPT - 1) / BPT;
  int i0 = blk * per_blk;
  int i1 = min(i0 + per_blk, NF4);
  const float4* base = (const float4*)(ea + (size_t)t*EE*DE);
  float s[8] = {0,0,0,0,0,0,0,0};
  for (int i = i0 + (int)threadIdx.x; i < i1; i += 256){
    float4 v = base[i];
    int db = (i & 1) * 4;
    s[db+0] += v.x; s[db+1] += v.y; s[db+2] += v.z; s[db+3] += v.w;
  }
  __shared__ float red[256];
  for (int d = 0; d < 8; d++){
    red[threadIdx.x] = s[d];
    __syncthreads();
    for (int off = 128; off > 0; off >>= 1){
      if (threadIdx.x < (unsigned)off) red[threadIdx.x] += red[threadIdx.x + off];
      __syncthreads();
    }
    if (threadIdx.x == 0) atomicAdd(&aggE[t*DE + d], red[0] / (float)EE);
    __syncthreads();
  }
}

// ---------------- hierarchical exclusive scan (2 kernels) ----------------
__global__ __launch_bounds__(256) void scan_blk(const int* __restrict__ deg, int* __restrict__ rp,
                                                int* __restrict__ bsum){
  __shared__ int sm[256];
  int i = blockIdx.x*256 + threadIdx.x;
  int v = (i < NN) ? deg[i] : 0;
  sm[threadIdx.x] = v;
  __syncthreads();
  #pragma unroll
  for (int off = 1; off < 256; off <<= 1){
    int t = (threadIdx.x >= (unsigned)off) ? sm[threadIdx.x - off] : 0;
    __syncthreads();
    sm[threadIdx.x] += t;
    __syncthreads();
  }
  if (i < NN) rp[i] = sm[threadIdx.x] - v;   // block-local exclusive
  if (threadIdx.x == 255) bsum[blockIdx.x] = sm[255];
}

// each block computes its own prefix of bsum (NB=196 <= 256: one LDS reduce pass)
__global__ __launch_bounds__(256) void scan_add(int* __restrict__ rp, const int* __restrict__ bsum,
                                                int* __restrict__ cursor){
  __shared__ int red[256];
  int t = threadIdx.x;
  red[t] = (t < (int)blockIdx.x) ? bsum[t] : 0;
  __syncthreads();
  #pragma unroll
  for (int off = 128; off > 0; off >>= 1){
    if (t < off) red[t] += red[t + off];
    __syncthreads();
  }
  int boffs = red[0];
  int i = blockIdx.x*256 + t;
  if (i < NN){
    int r = rp[i] + boffs;
    rp[i] = r;
    cursor[i] = r;
  }
  if (i == 0) rp[NN] = EE;
}

// scatter SRC VALUES (not edge ids): removes one indirection in the fused edge loop
__global__ void scatter_edges(const int* __restrict__ src, const int* __restrict__ dst,
                              int* __restrict__ cursor, int* __restrict__ srt){
  int i = blockIdx.x*256 + threadIdx.x;
  if (i < EE){ int pos = atomicAdd(&cursor[dst[i]], 1); srt[pos] = src[i]; }
}

// ---------------- layer-1 GEMMs with shared A strip in LDS ----------------
// grid (392, 2). y=0: A=x_pkg, 4 tiles (hs1 c0/c1, hs2 c0/c1). y=1: A=xd5, 2 tiles (hd1).
__global__ __launch_bounds__(256) void gemm_l1(const float* __restrict__ Apkg, const float* __restrict__ Adst,
                                               const unsigned short* __restrict__ Wtall,
                                               const float* __restrict__ mask,
                                               unsigned short* __restrict__ Chs1,
                                               unsigned short* __restrict__ Chs2,
                                               unsigned short* __restrict__ Chd1){
  __shared__ short Afull[128][136];
  __shared__ short Bl[128][56];
  int tid = threadIdx.x;
  int lane = tid & 63;
  int w = tid >> 6;
  int wm = w >> 1, wn = w & 1;
  int row0 = blockIdx.x * 128;
  int fr = lane & 15;
  int kb = lane >> 4;
  const float* A = blockIdx.y ? Adst : Apkg;
  #pragma unroll
  for (int p = 0; p < 8; p++){
    int idx = tid + p*256;
    int r = idx >> 4, ch = idx & 15;
    int gr = row0 + r;
    u16x8 o = (u16x8){0,0,0,0,0,0,0,0};
    if (gr < NN){
      float mv = mask[gr];
      const float* ap = A + (size_t)gr*DIN + ch*8;
      float4 a0 = *(const float4*)(ap);
      float4 a1 = *(const float4*)(ap + 4);
      o[0]=f2b(a0.x*mv); o[1]=f2b(a0.y*mv); o[2]=f2b(a0.z*mv); o[3]=f2b(a0.w*mv);
      o[4]=f2b(a1.x*mv); o[5]=f2b(a1.y*mv); o[6]=f2b(a1.z*mv); o[7]=f2b(a1.w*mv);
    }
    *(u16x8*)(&Afull[r][ch*8]) = o;
  }
  int ntile = blockIdx.y ? 2 : 4;
  #pragma unroll 1
  for (int t = 0; t < ntile; t++){
    int wsel = blockIdx.y ? 2 : (t >> 1);
    const unsigned short* Wt = Wtall + (size_t)wsel*256*DIN;
    unsigned short* Co = blockIdx.y ? Chd1 : ((t >> 1) ? Chs2 : Chs1);
    int col0 = (t & 1) * 128;
    f32x4 acc[4][4];
    #pragma unroll
    for (int i = 0; i < 4; i++)
      #pragma unroll
      for (int j = 0; j < 4; j++)
        acc[i][j] = (f32x4){0.f, 0.f, 0.f, 0.f};
    for (int k0 = 0; k0 < DIN; k0 += 32){
      bf16x8 rb[2];
      #pragma unroll
      for (int p = 0; p < 2; p++){
        int idx = tid + p*256;
        int r = idx >> 2, ch = idx & 3;
        rb[p] = *(const bf16x8*)(Wt + (size_t)(col0 + r)*DIN + k0 + ch*8);
      }
      __syncthreads();
      #pragma unroll
      for (int p = 0; p < 2; p++){
        int idx = tid + p*256;
        int r = idx >> 2, ch = idx & 3;
        *(bf16x8*)(&Bl[r][ch*8]) = rb[p];
      }
      __syncthreads();
      bf16x8 af[4], bfr[4];
      #pragma unroll
      for (int i = 0; i < 4; i++) af[i]  = *(const bf16x8*)(&Afull[wm*64 + i*16 + fr][k0 + kb*8]);
      #pragma unroll
      for (int j = 0; j < 4; j++) bfr[j] = *(const bf16x8*)(&Bl[wn*64 + j*16 + fr][kb*8]);
      #pragma unroll
      for (int i = 0; i < 4; i++)
        #pragma unroll
        for (int j = 0; j < 4; j++)
          acc[i][j] = __builtin_amdgcn_mfma_f32_16x16x32_bf16(af[i], bfr[j], acc[i][j], 0, 0, 0);
    }
    // C/D layout: col = lane&15, row = (lane>>4)*4 + q  (m89-verified)
    #pragma unroll
    for (int i = 0; i < 4; i++){
      #pragma unroll
      for (int q = 0; q < 4; q++){
        int grow = row0 + wm*64 + i*16 + kb*4 + q;
        if (grow < NN){
          #pragma unroll
          for (int j = 0; j < 4; j++)
            Co[(size_t)grow*256 + col0 + wn*64 + j*16 + fr] = f2b(acc[i][j][q]);
        }
      }
    }
  }
}

// ---------------- MFMA GEMM, bf16 A (h1 @ W2_dst), K=256 ----------------
__global__ __launch_bounds__(256) void gemm_bf16(const short* __restrict__ A, const short* __restrict__ Wt,
                                                 unsigned short* __restrict__ Cb, int M, int K){
  __shared__ short Al[128][56];
  __shared__ short Bl[128][56];
  int tid = threadIdx.x;
  int lane = tid & 63;
  int w = tid >> 6;
  int wm = w >> 1, wn = w & 1;
  int row0 = blockIdx.x * 128, col0 = blockIdx.y * 128;
  int fr = lane & 15;
  int kb = lane >> 4;
  f32x4 acc[4][4];
  #pragma unroll
  for (int i = 0; i < 4; i++)
    #pragma unroll
    for (int j = 0; j < 4; j++)
      acc[i][j] = (f32x4){0.f, 0.f, 0.f, 0.f};

  for (int k0 = 0; k0 < K; k0 += 32){
    bf16x8 ra[2], rb[2];
    #pragma unroll
    for (int p = 0; p < 2; p++){
      int idx = tid + p*256;
      int r = idx >> 2, ch = idx & 3;
      int gr = row0 + r;
      if (gr < M) ra[p] = *(const bf16x8*)(A + (size_t)gr*K + k0 + ch*8);
      else        ra[p] = (bf16x8){0,0,0,0,0,0,0,0};
      rb[p] = *(const bf16x8*)(Wt + (size_t)(col0 + r)*K + k0 + ch*8);
    }
    __syncthreads();
    #pragma unroll
    for (int p = 0; p < 2; p++){
      int idx = tid + p*256;
      int r = idx >> 2, ch = idx & 3;
      *(bf16x8*)(&Al[r][ch*8]) = ra[p];
      *(bf16x8*)(&Bl[r][ch*8]) = rb[p];
    }
    __syncthreads();
    bf16x8 af[4], bfr[4];
    #pragma unroll
    for (int i = 0; i < 4; i++) af[i]  = *(const bf16x8*)(&Al[wm*64 + i*16 + fr][kb*8]);
    #pragma unroll
    for (int j = 0; j < 4; j++) bfr[j] = *(const bf16x8*)(&Bl[wn*64 + j*16 + fr][kb*8]);
    #pragma unroll
    for (int i = 0; i < 4; i++)
      #pragma unroll
      for (int j = 0; j < 4; j++)
        acc[i][j] = __builtin_amdgcn_mfma_f32_16x16x32_bf16(af[i], bfr[j], acc[i][j], 0, 0, 0);
  }
  #pragma unroll
  for (int i = 0; i < 4; i++){
    #pragma unroll
    for (int q = 0; q < 4; q++){
      int grow = row0 + wm*64 + i*16 + kb*4 + q;
      if (grow < M){
        #pragma unroll
        for (int j = 0; j < 4; j++)
          Cb[(size_t)grow*256 + col0 + wn*64 + j*16 + fr] = f2b(acc[i][j][q]);
      }
    }
  }
}

// ---------------- FUSED GAT edge phase: logits + exp + weighted aggregation ----------------
// Wave per dst node; srt[] = pre-gathered src ids. Unrolled x4 (mean degree = 4).
__global__ __launch_bounds__(256) void gat_fused(const int* __restrict__ rp, const int* __restrict__ srt,
                                                 const unsigned short* __restrict__ hs,
                                                 const unsigned short* __restrict__ hd,
                                                 const float* __restrict__ att, const float* __restrict__ bias,
                                                 unsigned short* __restrict__ outb, int do_relu){
  int n = blockIdx.x*4 + (threadIdx.x >> 6);
  int lane = threadIdx.x & 63;
  if (n >= NN) return;
  const float4 av = *(const float4*)(att + lane*4);
  ushort4 ud = *(const ushort4*)(hd + (size_t)n*256 + lane*4);
  float d0 = b2f(ud.x), d1 = b2f(ud.y), d2 = b2f(ud.z), d3 = b2f(ud.w);
  int beg = rp[n], end = rp[n+1];
  float4 acc = {0.f,0.f,0.f,0.f};
  float sw = 0.f;
  int i = beg;
  for (; i + 3 < end; i += 4){
    int sA = srt[i], sB = srt[i+1], sC = srt[i+2], sD = srt[i+3];
    ushort4 uA = *(const ushort4*)(hs + (size_t)sA*256 + lane*4);
    ushort4 uB = *(const ushort4*)(hs + (size_t)sB*256 + lane*4);
    ushort4 uC = *(const ushort4*)(hs + (size_t)sC*256 + lane*4);
    ushort4 uD = *(const ushort4*)(hs + (size_t)sD*256 + lane*4);
    float hA0=b2f(uA.x), hA1=b2f(uA.y), hA2=b2f(uA.z), hA3=b2f(uA.w);
    float hB0=b2f(uB.x), hB1=b2f(uB.y), hB2=b2f(uB.z), hB3=b2f(uB.w);
    float hC0=b2f(uC.x), hC1=b2f(uC.y), hC2=b2f(uC.z), hC3=b2f(uC.w);
    float hD0=b2f(uD.x), hD1=b2f(uD.y), hD2=b2f(uD.z), hD3=b2f(uD.w);
    float mA0=hA0+d0, mA1=hA1+d1, mA2=hA2+d2, mA3=hA3+d3;
    float mB0=hB0+d0, mB1=hB1+d1, mB2=hB2+d2, mB3=hB3+d3;
    float mC0=hC0+d0, mC1=hC1+d1, mC2=hC2+d2, mC3=hC3+d3;
    float mD0=hD0+d0, mD1=hD1+d1, mD2=hD2+d2, mD3=hD3+d3;
    mA0=(mA0>0.f)?mA0:0.2f*mA0; mB0=(mB0>0.f)?mB0:0.2f*mB0; mC0=(mC0>0.f)?mC0:0.2f*mC0; mD0=(mD0>0.f)?mD0:0.2f*mD0;
    mA1=(mA1>0.f)?mA1:0.2f*mA1; mB1=(mB1>0.f)?mB1:0.2f*mB1; mC1=(mC1>0.f)?mC1:0.2f*mC1; mD1=(mD1>0.f)?mD1:0.2f*mD1;
    mA2=(mA2>0.f)?mA2:0.2f*mA2; mB2=(mB2>0.f)?mB2:0.2f*mB2; mC2=(mC2>0.f)?mC2:0.2f*mC2; mD2=(mD2>0.f)?mD2:0.2f*mD2;
    mA3=(mA3>0.f)?mA3:0.2f*mA3; mB3=(mB3>0.f)?mB3:0.2f*mB3; mC3=(mC3>0.f)?mC3:0.2f*mC3; mD3=(mD3>0.f)?mD3:0.2f*mD3;
    float pA = mA0*av.x + mA1*av.y + mA2*av.z + mA3*av.w;
    float pB = mB0*av.x + mB1*av.y + mB2*av.z + mB3*av.w;
    float pC = mC0*av.x + mC1*av.y + mC2*av.z + mC3*av.w;
    float pD = mD0*av.x + mD1*av.y + mD2*av.z + mD3*av.w;
    #pragma unroll
    for (int msk = 8; msk > 0; msk >>= 1){
      pA += __shfl_xor(pA, msk); pB += __shfl_xor(pB, msk);
      pC += __shfl_xor(pC, msk); pD += __shfl_xor(pD, msk);
    }
    float wA = expf(fminf(pA, 80.f));
    float wB = expf(fminf(pB, 80.f));
    float wC = expf(fminf(pC, 80.f));
    float wD = expf(fminf(pD, 80.f));
    acc.x = fmaf(wA, hA0, fmaf(wB, hB0, fmaf(wC, hC0, fmaf(wD, hD0, acc.x))));
    acc.y = fmaf(wA, hA1, fmaf(wB, hB1, fmaf(wC, hC1, fmaf(wD, hD1, acc.y))));
    acc.z = fmaf(wA, hA2, fmaf(wB, hB2, fmaf(wC, hC2, fmaf(wD, hD2, acc.z))));
    acc.w = fmaf(wA, hA3, fmaf(wB, hB3, fmaf(wC, hC3, fmaf(wD, hD3, acc.w))));
    sw += (wA + wB) + (wC + wD);
  }
  for (; i < end; i++){
    int s = srt[i];
    ushort4 uh = *(const ushort4*)(hs + (size_t)s*256 + lane*4);
    float h0 = b2f(uh.x), h1 = b2f(uh.y), h2 = b2f(uh.z), h3 = b2f(uh.w);
    float m0 = h0 + d0, m1 = h1 + d1, m2 = h2 + d2, m3 = h3 + d3;
    m0 = (m0 > 0.f) ? m0 : 0.2f*m0;
    m1 = (m1 > 0.f) ? m1 : 0.2f*m1;
    m2 = (m2 > 0.f) ? m2 : 0.2f*m2;
    m3 = (m3 > 0.f) ? m3 : 0.2f*m3;
    float p = m0*av.x + m1*av.y + m2*av.z + m3*av.w;
    #pragma unroll
    for (int msk = 8; msk > 0; msk >>= 1) p += __shfl_xor(p, msk);
    float wv = expf(fminf(p, 80.f));
    acc.x = fmaf(wv, h0, acc.x);
    acc.y = fmaf(wv, h1, acc.y);
    acc.z = fmaf(wv, h2, acc.z);
    acc.w = fmaf(wv, h3, acc.w);
    sw += wv;
  }
  float inv = 1.f / (sw + 1e-16f);
  const float4 b4 = *(const float4*)(bias + lane*4);
  float4 r;
  r.x = acc.x*inv + b4.x;
  r.y = acc.y*inv + b4.y;
  r.z = acc.z*inv + b4.z;
  r.w = acc.w*inv + b4.w;
  if (do_relu){
    r.x = fmaxf(r.x, 0.f); r.y = fmaxf(r.y, 0.f);
    r.z = fmaxf(r.z, 0.f); r.w = fmaxf(r.w, 0.f);
  }
  ushort4 o;
  o.x = f2b(r.x); o.y = f2b(r.y); o.z = f2b(r.z); o.w = f2b(r.w);
  *(ushort4*)(outb + (size_t)n*256 + lane*4) = o;
}

// ---------------- pool logits via MFMA + in-register row softmax -> sass bf16 [NN][48] ----------------
__global__ __launch_bounds__(256) void pool_logits_mfma(const unsigned short* __restrict__ h2b,
                                                        const float* __restrict__ Wp,
                                                        const float* __restrict__ bp,
                                                        unsigned short* __restrict__ sass,
                                                        float* __restrict__ xp){
  __shared__ short Al[128][56];    // h2 tile, BK=32
  __shared__ short Bn[KC][264];    // Wp^T, full K=256 (pad 8)
  int tid = threadIdx.x;
  int lane = tid & 63;
  int w = tid >> 6;
  int row0 = blockIdx.x * 128;
  int fr = lane & 15;
  int kb = lane >> 4;
  if (blockIdx.x == 0){
    for (int i = tid; i < KC*FDIM; i += 256) xp[i] = 0.f;
  }
  for (int idx = tid; idx < 256*KC; idx += 256){
    int k = idx / KC, n = idx % KC;
    Bn[n][k] = f2b(Wp[idx]);
  }
  f32x4 acc[2][3];
  #pragma unroll
  for (int i = 0; i < 2; i++)
    #pragma unroll
    for (int j = 0; j < 3; j++)
      acc[i][j] = (f32x4){0.f, 0.f, 0.f, 0.f};

  for (int k0 = 0; k0 < 256; k0 += 32){
    bf16x8 ra[2];
    #pragma unroll
    for (int p = 0; p < 2; p++){
      int idx = tid + p*256;
      int r = idx >> 2, ch = idx & 3;
      int gr = row0 + r;
      if (gr < NN) ra[p] = *(const bf16x8*)((const short*)h2b + (size_t)gr*256 + k0 + ch*8);
      else         ra[p] = (bf16x8){0,0,0,0,0,0,0,0};
    }
    __syncthreads();
    #pragma unroll
    for (int p = 0; p < 2; p++){
      int idx = tid + p*256;
      int r = idx >> 2, ch = idx & 3;
      *(bf16x8*)(&Al[r][ch*8]) = ra[p];
    }
    __syncthreads();
    bf16x8 af[2], bfr[3];
    #pragma unroll
    for (int i = 0; i < 2; i++) af[i]  = *(const bf16x8*)(&Al[w*32 + i*16 + fr][kb*8]);
    #pragma unroll
    for (int j = 0; j < 3; j++) bfr[j] = *(const bf16x8*)(&Bn[j*16 + fr][k0 + kb*8]);
    #pragma unroll
    for (int i = 0; i < 2; i++)
      #pragma unroll
      for (int j = 0; j < 3; j++)
        acc[i][j] = __builtin_amdgcn_mfma_f32_16x16x32_bf16(af[i], bfr[j], acc[i][j], 0, 0, 0);
  }
  float bb[3];
  #pragma unroll
  for (int j = 0; j < 3; j++) bb[j] = bp[j*16 + fr];
  #pragma unroll
  for (int i = 0; i < 2; i++){
    #pragma unroll
    for (int q = 0; q < 4; q++){
      int grow = row0 + w*32 + i*16 + kb*4 + q;
      float v0 = acc[i][0][q] + bb[0];
      float v1 = acc[i][1][q] + bb[1];
      float v2 = acc[i][2][q] + bb[2];
      float m = fmaxf(v0, fmaxf(v1, v2));
      #pragma unroll
      for (int msk = 8; msk > 0; msk >>= 1) m = fmaxf(m, __shfl_xor(m, msk));
      float e0 = expf(v0 - m), e1 = expf(v1 - m), e2 = expf(v2 - m);
      float s = e0 + e1 + e2;
      #pragma unroll
      for (int msk = 8; msk > 0; msk >>= 1) s += __shfl_xor(s, msk);
      float inv = 1.f / s;
      if (grow < NN){
        unsigned short* so = sass + (size_t)grow*KC;
        so[fr]      = f2b(e0 * inv);
        so[16 + fr] = f2b(e1 * inv);
        so[32 + fr] = f2b(e2 * inv);
      }
    }
  }
}

// ---------------- x_pooled partials: s.T @ h2 over 64-node chunks (1 chunk/block) ----------------
#define PCH 64
#define NPART ((NN + PCH - 1)/PCH)   // 782
__global__ __launch_bounds__(256) void pooled_partial(const unsigned short* __restrict__ sass,
                                                      const unsigned short* __restrict__ h2b,
                                                      float* __restrict__ part){
  __shared__ float sld[PCH][KC];
  int t = threadIdx.x;
  int base = blockIdx.x * PCH;
  int cnt = min(PCH, NN - base);
  for (int idx = t; idx < cnt*KC; idx += 256)
    sld[idx/KC][idx%KC] = b2f(sass[(size_t)(base + idx/KC)*KC + idx%KC]);
  __syncthreads();
  float acc[KC];
  #pragma unroll
  for (int k = 0; k < KC; k++) acc[k] = 0.f;
  for (int n = 0; n < cnt; n++){
    float v = b2f(h2b[(size_t)(base + n)*256 + t]);
    #pragma unroll
    for (int k = 0; k < KC; k++) acc[k] = fmaf(sld[n][k], v, acc[k]);
  }
  float* po = part + (size_t)blockIdx.x*KC*256;
  #pragma unroll
  for (int k = 0; k < KC; k++) po[k*256 + t] = acc[k];
}

#define PSPL 8
__global__ __launch_bounds__(256) void pooled_reduce(const float* __restrict__ part, float* __restrict__ xp){
  int idx = blockIdx.x*256 + threadIdx.x;     // 0..12287
  const int per = (NPART + PSPL - 1)/PSPL;    // 98
  int p0 = blockIdx.y * per;
  int p1 = min(p0 + per, NPART);
  float s0 = 0.f, s1 = 0.f;
  int p = p0;
  for (; p + 1 < p1; p += 2){
    s0 += part[(size_t)p*KC*256 + idx];
    s1 += part[(size_t)(p+1)*KC*256 + idx];
  }
  if (p < p1) s0 += part[(size_t)p*KC*256 + idx];
  atomicAdd(&xp[idx], s0 + s1);
}

// ---------------- final classifier ----------------
__global__ void final_cls(const float* __restrict__ xp, const float* __restrict__ agg,
                          const float* __restrict__ Wc, const float* __restrict__ bc,
                          float* __restrict__ out){
  int k = threadIdx.x;
  if (k < KC){
    float s = bc[0];
    for (int f = 0; f < 256; f++) s = fmaf(xp[k*256 + f], Wc[f], s);
    s = fmaf(agg[k], Wc[256], s);
    out[k] = 1.f/(1.f + expf(-s));
  }
}

extern "C" void kernel_launch(void* const* d_in, const int* in_sizes, int n_in,
                              void* d_out, int out_size, void* d_ws, size_t ws_size,
                              hipStream_t stream) {
  const float* x_pkg     = (const float*)d_in[0];
  const float* x_dst     = (const float*)d_in[1];
  const float* edge_attr = (const float*)d_in[2];
  const float* node_mask = (const float*)d_in[3];
  const float* W1_src    = (const float*)d_in[4];
  const float* W1_dst    = (const float*)d_in[5];
  const float* att1      = (const float*)d_in[6];
  const float* b1        = (const float*)d_in[7];
  const float* W2_src    = (const float*)d_in[8];
  const float* W2_dst    = (const float*)d_in[9];
  const float* att2      = (const float*)d_in[10];
  const float* b2        = (const float*)d_in[11];
  const float* W_pool    = (const float*)d_in[12];
  const float* b_pool    = (const float*)d_in[13];
  const float* W_cls     = (const float*)d_in[14];
  const float* b_cls     = (const float*)d_in[15];
  const int*   edge_index= (const int*)d_in[16];
  float* out = (float*)d_out;

  const int T5 = TT - 1;
  const float* W1s5 = W1_src + (size_t)T5*DIN*FDIM;
  const float* W1d5 = W1_dst + (size_t)T5*DIN*FDIM;
  const float* a1_5 = att1   + (size_t)T5*FDIM;
  const float* b1_5 = b1     + (size_t)T5*FDIM;
  const float* W2s5 = W2_src + (size_t)T5*DIN*FDIM;
  const float* W2d5 = W2_dst + (size_t)T5*FDIM*FDIM;
  const float* a2_5 = att2   + (size_t)T5*FDIM;
  const float* b2_5 = b2     + (size_t)T5*FDIM;
  const float* xd5  = x_dst  + (size_t)T5*NN*DIN;
  const int* src5   = edge_index + (size_t)T5*2*EE;
  const int* dst5   = src5 + EE;

  // ---- workspace layout (bf16 overlays inside three f32-sized slots) ----
  float* buf0 = (float*)d_ws;            // hs1b|hs2b (bf16) -> pooled partials (f32, 38.4MB)
  float* buf1 = buf0 + (size_t)NN*FDIM;  // hd1b|h1b (bf16)  -> h2b (bf16)
  float* buf2 = buf1 + (size_t)NN*FDIM;  // hd2b (bf16) -> sass (bf16 [NN][48])
  float* xpool= buf2 + (size_t)NN*FDIM;  // [KC*256]
  float* aggE = xpool + KC*FDIM;         // [64]
  int* deg    = (int*)(aggE + 64);
  int* rp     = deg + NN;
  int* cursor = rp + NN + 1;
  int* srt    = cursor + NN;             // [EE] pre-gathered src ids
  unsigned short* Wtall = (unsigned short*)(srt + EE);   // stacked [768][128]: W1s,W2s,W1d
  unsigned short* Wt2d  = Wtall + (size_t)3*256*DIN;     // [256][256]
  int* bsum = (int*)(Wt2d + (size_t)256*FDIM);   // [NB]
  // bf16 overlays:
  unsigned short* hs1b = (unsigned short*)buf0;                   // dead after L1 fused
  unsigned short* hs2b = hs1b + (size_t)NN*FDIM;                  // dead after L2 fused
  unsigned short* hd1b = (unsigned short*)buf1;                   // dead after L1 fused
  unsigned short* h1b  = hd1b + (size_t)NN*FDIM;                  // dead after hd2 gemm
  unsigned short* h2b  = (unsigned short*)buf1;                   // L2 fused output
  unsigned short* hd2b = (unsigned short*)buf2;                   // dead after L2 fused
  unsigned short* sass = (unsigned short*)buf2;                   // pool softmax out [NN][48]

  // init (weights + zeroing) and CSR build
  init_misc<<<dim3(256, 5), 256, 0, stream>>>(W1s5, W2s5, W1d5, W2d5, Wtall, Wt2d, deg, (int*)aggE);
  count_and_mean<<<CDB + TT*BPT, 256, 0, stream>>>(dst5, deg, edge_attr, aggE);
  scan_blk<<<NB, 256, 0, stream>>>(deg, rp, bsum);
  scan_add<<<NB, 256, 0, stream>>>(rp, bsum, cursor);
  scatter_edges<<<(EE+255)/256, 256, 0, stream>>>(src5, dst5, cursor, srt);

  // layer 1: hs1 | hs2 | hd1 with A strips staged once per block
  gemm_l1<<<dim3((NN + 127)/128, 2), 256, 0, stream>>>(x_pkg, xd5, Wtall, node_mask,
                                                        hs1b, hs2b, hd1b);
  gat_fused<<<NN/4, 256, 0, stream>>>(rp, srt, hs1b, hd1b, a1_5, b1_5, h1b, 1);   // h1 -> bf16

  // layer 2
  gemm_bf16<<<dim3((NN + 127)/128, 2), 256, 0, stream>>>((const short*)h1b, (const short*)Wt2d,
                                                          hd2b, NN, FDIM);          // hd2
  gat_fused<<<NN/4, 256, 0, stream>>>(rp, srt, hs2b, hd2b, a2_5, b2_5, h2b, 0);   // h2 -> bf16

  // pooling + classifier (sass overlays dead hd2b; partials in dead buf0)
  pool_logits_mfma<<<(NN + 127)/128, 256, 0, stream>>>(h2b, W_pool, b_pool, sass, xpool);
  pooled_partial<<<NPART, 256, 0, stream>>>(sass, h2b, buf0);
  pooled_reduce<<<dim3(KC, PSPL), 256, 0, stream>>>(buf0, xpool);
  final_cls<<<1, 64, 0, stream>>>(xpool, aggE, W_cls, b_cls, out);
}